// Round 12
// baseline (352.370 us; speedup 1.0000x reference)
//
#include <hip/hip_runtime.h>
#include <hip/hip_bf16.h>
#include <math.h>

#define N_NODES 65536
#define N_EDGES 524288
#define IN_CH 128
#define HC 64
#define N_GRAPHS 512
#define BUCKET_CAP 32

typedef __attribute__((ext_vector_type(8))) short short8v;
typedef __attribute__((ext_vector_type(4))) float float4v;

__device__ __forceinline__ ushort f32_to_bf16_rne(float x) {
    unsigned u = __float_as_uint(x);
    return (ushort)((u + 0x7fffu + ((u >> 16) & 1u)) >> 16);
}
__device__ __forceinline__ float bf16_to_f32(ushort h) {
    return __uint_as_float(((unsigned)h) << 16);
}

// 48-byte bucket entry: edge features inlined so aggregate never does the
// random 32B ea gather (was ~50-67 MB/dispatch of line over-fetch).
struct __align__(16) BEntry {
    float4 ea0;
    float4 ea1;
    int src;
    int pad[3];
};

// ---------------------------------------------------------------------------
// Build per-destination edge buckets with inlined edge features.
// ea read is fully coalesced (edge order); entry write is scattered (once).
// ---------------------------------------------------------------------------
__global__ void build_buckets(const int* __restrict__ ei,
                              const float* __restrict__ ea,
                              int* __restrict__ cnt,
                              BEntry* __restrict__ bucket) {
    int e = blockIdx.x * 256 + threadIdx.x;
    if (e >= N_EDGES) return;
    int s = ei[e];
    int d = ei[N_EDGES + e];
    float4 a0 = *(const float4*)(ea + (size_t)e * 8);
    float4 a1 = *(const float4*)(ea + (size_t)e * 8 + 4);
    int pos = atomicAdd(&cnt[d], 1);
    if (pos < BUCKET_CAP) {
        BEntry* be = &bucket[(size_t)d * BUCKET_CAP + pos];
        be->ea0 = a0;
        be->ea1 = a1;
        be->src = s;
    }
}

// ---------------------------------------------------------------------------
// Pack the 8 projection matrices into MFMA B-fragment order, split bf16
// hi/lo (Markidis). Fragment f=(ks*4+ct)*64+lane, element j:
//   W[ks*32 + (lane>>4)*8 + j][ct*16 + (lane&15)]
// ---------------------------------------------------------------------------
__global__ void pack_weights(
    const float* __restrict__ Wq1, const float* __restrict__ Wk1,
    const float* __restrict__ Wv1, const float* __restrict__ Ws1,
    const float* __restrict__ Wq2, const float* __restrict__ Wk2,
    const float* __restrict__ Wv2, const float* __restrict__ Ws2,
    ushort* __restrict__ wf1_hi, ushort* __restrict__ wf1_lo,
    ushort* __restrict__ wf2_hi, ushort* __restrict__ wf2_lo) {
    int f = blockIdx.x * 256 + threadIdx.x;
    if (f >= 6144) return;
    const float* W;
    ushort *ph, *pl;
    int fl;
    if (f < 4096) {
        int mat = f >> 10; fl = f & 1023;
        W = (mat == 0) ? Wq1 : (mat == 1) ? Wk1 : (mat == 2) ? Wv1 : Ws1;
        ph = wf1_hi + (size_t)mat * 1024 * 8;
        pl = wf1_lo + (size_t)mat * 1024 * 8;
    } else {
        int g = f - 4096;
        int mat = g >> 9; fl = g & 511;
        W = (mat == 0) ? Wq2 : (mat == 1) ? Wk2 : (mat == 2) ? Wv2 : Ws2;
        ph = wf2_hi + (size_t)mat * 512 * 8;
        pl = wf2_lo + (size_t)mat * 512 * 8;
    }
    int lane = fl & 63;
    int ct = (fl >> 6) & 3;
    int ks = fl >> 8;
    int col = ct * 16 + (lane & 15);
    int k0 = ks * 32 + (lane >> 4) * 8;
    ushort h8[8], l8[8];
#pragma unroll
    for (int j = 0; j < 8; ++j) {
        float w = W[(size_t)(k0 + j) * HC + col];
        ushort h = f32_to_bf16_rne(w);
        float r = w - bf16_to_f32(h);
        h8[j] = h;
        l8[j] = f32_to_bf16_rne(r);
    }
    *(uint4*)&ph[(size_t)fl * 8] = *(uint4*)h8;
    *(uint4*)&pl[(size_t)fl * 8] = *(uint4*)l8;
}

// ---------------------------------------------------------------------------
// MFMA node GEMM (split-bf16, 3 passes, f32 acc). 256 thr = 4 waves,
// 128 nodes/block. kv output now per-channel float2 interleaved:
// kv[n*128 + 2*ch] = k_ch, kv[n*128 + 2*ch + 1] = v_ch, so the aggregate
// gather is ONE float2 load per lane per edge (512B contiguous per node).
// ---------------------------------------------------------------------------
template <int FIN>
__global__ __launch_bounds__(256, 2) void node_gemm_mfma(
    const float* __restrict__ xin,
    const ushort* __restrict__ wf_hi, const ushort* __restrict__ wf_lo,
    const float* __restrict__ bq, const float* __restrict__ bk,
    const float* __restrict__ bv, const float* __restrict__ bs,
    float* __restrict__ q, float* __restrict__ kv, float* __restrict__ hout) {
    constexpr int NPB = 128;
    constexpr int KS = FIN / 32;
    constexpr int KC = FIN / 8;
    __shared__ ushort xs[2 * NPB * KC * 8];
    constexpr int LOHALF = NPB * KC * 8;
    const int tid = threadIdx.x;
    const int lane = tid & 63;
    const int w = tid >> 6;
    const int n0 = blockIdx.x * NPB;

    for (int c = tid; c < NPB * KC; c += 256) {
        int r = c / KC, kc = c % KC;
        const float4* src = (const float4*)(xin + (size_t)(n0 + r) * FIN + kc * 8);
        float4 x0 = src[0], x1 = src[1];
        float xv[8] = {x0.x, x0.y, x0.z, x0.w, x1.x, x1.y, x1.z, x1.w};
        ushort h[8], l[8];
#pragma unroll
        for (int j = 0; j < 8; ++j) {
            h[j] = f32_to_bf16_rne(xv[j]);
            l[j] = f32_to_bf16_rne(xv[j] - bf16_to_f32(h[j]));
        }
        int kcs = kc ^ (r & 7);
        *(uint4*)&xs[(size_t)(r * KC + kcs) * 8] = *(uint4*)h;
        *(uint4*)&xs[LOHALF + (size_t)(r * KC + kcs) * 8] = *(uint4*)l;
    }

    const int ch16 = lane & 15;
    float bqv[4], bkv[4], bvv[4], bsv[4];
#pragma unroll
    for (int ct = 0; ct < 4; ++ct) {
        bqv[ct] = bq[ct * 16 + ch16];
        bkv[ct] = bk[ct * 16 + ch16];
        bvv[ct] = bv[ct * 16 + ch16];
        bsv[ct] = bs[ct * 16 + ch16];
    }
    float4v acc[2][16];
#pragma unroll
    for (int t = 0; t < 16; ++t) {
        int mat = t >> 2, ct = t & 3;
        float b = (mat == 0) ? bqv[ct] : (mat == 1) ? bkv[ct]
                : (mat == 2) ? bvv[ct] : bsv[ct];
        acc[0][t] = (float4v){b, b, b, b};
        acc[1][t] = (float4v){b, b, b, b};
    }
    __syncthreads();

    const int g = lane >> 4;
    for (int ks = 0; ks < KS; ++ks) {
        short8v ah[2], al[2];
#pragma unroll
        for (int mt = 0; mt < 2; ++mt) {
            int r = w * 32 + mt * 16 + (lane & 15);
            int kcs = (ks * 4 + g) ^ (r & 7);
            ah[mt] = *(const short8v*)&xs[(size_t)(r * KC + kcs) * 8];
            al[mt] = *(const short8v*)&xs[LOHALF + (size_t)(r * KC + kcs) * 8];
        }
#pragma unroll
        for (int t = 0; t < 16; ++t) {
            int mat = t >> 2, ct = t & 3;
            size_t fo = (((size_t)mat * KS * 4) + ks * 4 + ct) * 64 + lane;
            short8v bh = *(const short8v*)&wf_hi[fo * 8];
            short8v bl = *(const short8v*)&wf_lo[fo * 8];
            acc[0][t] = __builtin_amdgcn_mfma_f32_16x16x32_bf16(ah[0], bh, acc[0][t], 0, 0, 0);
            acc[1][t] = __builtin_amdgcn_mfma_f32_16x16x32_bf16(ah[1], bh, acc[1][t], 0, 0, 0);
            acc[0][t] = __builtin_amdgcn_mfma_f32_16x16x32_bf16(al[0], bh, acc[0][t], 0, 0, 0);
            acc[1][t] = __builtin_amdgcn_mfma_f32_16x16x32_bf16(al[1], bh, acc[1][t], 0, 0, 0);
            acc[0][t] = __builtin_amdgcn_mfma_f32_16x16x32_bf16(ah[0], bl, acc[0][t], 0, 0, 0);
            acc[1][t] = __builtin_amdgcn_mfma_f32_16x16x32_bf16(ah[1], bl, acc[1][t], 0, 0, 0);
        }
    }

    const int rloc = (lane >> 4) * 4;
#pragma unroll
    for (int mt = 0; mt < 2; ++mt) {
        int nbase = n0 + w * 32 + mt * 16 + rloc;
#pragma unroll
        for (int ct = 0; ct < 4; ++ct) {
            int ch = ct * 16 + ch16;
#pragma unroll
            for (int r2 = 0; r2 < 4; ++r2) {
                int n = nbase + r2;
                q[(size_t)n * HC + ch] = acc[mt][ct][r2];
                *(float2*)&kv[(size_t)n * 128 + 2 * ch] =
                    make_float2(acc[mt][4 + ct][r2], acc[mt][8 + ct][r2]);
                hout[(size_t)n * HC + ch] = acc[mt][12 + ct][r2];
            }
        }
    }
}

// ---------------------------------------------------------------------------
// DPP-based 16-lane sum (broadcast). VALU-only.
// ---------------------------------------------------------------------------
__device__ __forceinline__ float dpp_sum16(float x) {
    int t;
    t = __builtin_amdgcn_update_dpp(0, __float_as_int(x), 0xB1, 0xF, 0xF, true);
    x += __int_as_float(t);
    t = __builtin_amdgcn_update_dpp(0, __float_as_int(x), 0x4E, 0xF, 0xF, true);
    x += __int_as_float(t);
    t = __builtin_amdgcn_update_dpp(0, __float_as_int(x), 0x141, 0xF, 0xF, true);
    x += __int_as_float(t);
    t = __builtin_amdgcn_update_dpp(0, __float_as_int(x), 0x140, 0xF, 0xF, true);
    x += __int_as_float(t);
    return x;
}

// ---------------------------------------------------------------------------
// Per-destination-node aggregation, in-register online softmax (pairwise).
// Per edge now: 2 broadcast loads (entry ea) + 1 float2 gather (kv) — the
// eid indirection and the random ea gather are gone.
// ---------------------------------------------------------------------------
template <int RELU>
__global__ __launch_bounds__(256) void aggregate(
    const float* __restrict__ q, const float* __restrict__ kv,
    const float* __restrict__ We, const float* __restrict__ be,
    const int* __restrict__ cnt,
    const BEntry* __restrict__ bucket, float* __restrict__ hout) {
    const int wave = threadIdx.x >> 6;
    const int c = threadIdx.x & 63;
    const int n = blockIdx.x * 4 + wave;

    const float qc = q[n * HC + c] * 0.25f;
    int deg = cnt[n];
    if (deg > BUCKET_CAP) deg = BUCKET_CAP;

    const BEntry* bkt = bucket + (size_t)n * BUCKET_CAP;

    // lane-parallel prefetch of src ids (stride-48B but only deg lanes)
    int mysrc = 0;
    if (c < deg) mysrc = bkt[c].src;

    const float bec = be[c];
    float wec[8];
#pragma unroll
    for (int f = 0; f < 8; ++f) wec[f] = We[f * HC + c];

    float m = -INFINITY, d = 0.f, o = 0.f;

    float4 eA0, eA1, eB0, eB1, nA0, nA1, nB0, nB1;
    float2 kvA, kvB, nkvA, nkvB;

#define LOAD_EDGE(idx, E0, E1, KV)                                       \
    {                                                                    \
        int s_ = __builtin_amdgcn_readlane(mysrc, (idx));                \
        const BEntry* be_ = bkt + (idx);                                 \
        E0 = be_->ea0;                                                   \
        E1 = be_->ea1;                                                   \
        KV = *(const float2*)&kv[(size_t)s_ * 128 + 2 * c];              \
    }

#define EDGE_PROJ(E0, E1, EC)                                            \
    float EC = bec;                                                      \
    EC = fmaf(E0.x, wec[0], EC); EC = fmaf(E0.y, wec[1], EC);            \
    EC = fmaf(E0.z, wec[2], EC); EC = fmaf(E0.w, wec[3], EC);            \
    EC = fmaf(E1.x, wec[4], EC); EC = fmaf(E1.y, wec[5], EC);            \
    EC = fmaf(E1.z, wec[6], EC); EC = fmaf(E1.w, wec[7], EC);

    const int npairs = deg >> 1;

    if (deg >= 2) {
        LOAD_EDGE(0, eA0, eA1, kvA);
        LOAD_EDGE(1, eB0, eB1, kvB);
    } else if (deg == 1) {
        LOAD_EDGE(0, eA0, eA1, kvA);
    }

    for (int p = 0; p < npairs; ++p) {
        int base = (p + 1) * 2;
        if (base + 1 < deg) {
            LOAD_EDGE(base, nA0, nA1, nkvA);
            LOAD_EDGE(base + 1, nB0, nB1, nkvB);
        } else if (base < deg) {
            LOAD_EDGE(base, nA0, nA1, nkvA);
        }

        EDGE_PROJ(eA0, eA1, ecA);
        EDGE_PROJ(eB0, eB1, ecB);

        float pA = dpp_sum16(qc * (kvA.x + ecA));
        float pB = dpp_sum16(qc * (kvB.x + ecB));

        float newm = fmaxf(m, fmaxf(pA, pB));
        float scale = __expf(m - newm);
        float wA = __expf(pA - newm);
        float wB = __expf(pB - newm);
        d = d * scale + wA + wB;
        o = o * scale + (kvA.y + ecA) * wA + (kvB.y + ecB) * wB;
        m = newm;

        eA0 = nA0; eA1 = nA1; kvA = nkvA;
        eB0 = nB0; eB1 = nB1; kvB = nkvB;
    }

    if (deg & 1) {
        EDGE_PROJ(eA0, eA1, ecA);
        float pA = dpp_sum16(qc * (kvA.x + ecA));
        float newm = fmaxf(m, pA);
        float scale = __expf(m - newm);
        float wA = __expf(pA - newm);
        d = d * scale + wA;
        o = o * scale + (kvA.y + ecA) * wA;
    }

#undef LOAD_EDGE
#undef EDGE_PROJ

    float msg = (deg > 0) ? (o / d) : 0.f;
    float val = hout[n * HC + c] + msg;
    if (RELU) val = fmaxf(val, 0.f);
    hout[n * HC + c] = val;
}

// ---------------------------------------------------------------------------
// Mean pool (binary-search ranges over sorted batch).
// ---------------------------------------------------------------------------
__device__ __forceinline__ int lower_bound(const int* __restrict__ b, int val) {
    int lo = 0, hi = N_NODES;
    while (lo < hi) {
        int mid = (lo + hi) >> 1;
        if (b[mid] < val) lo = mid + 1; else hi = mid;
    }
    return lo;
}

__global__ __launch_bounds__(256) void pool_graph(const float* __restrict__ h,
                                                  const int* __restrict__ batch,
                                                  float* __restrict__ out) {
    const int g = blockIdx.x * 4 + (threadIdx.x >> 6);
    const int c = threadIdx.x & 63;
    const int s = lower_bound(batch, g);
    const int e = lower_bound(batch, g + 1);

    float a0 = 0.f, a1 = 0.f, a2 = 0.f, a3 = 0.f;
    int i = s;
    for (; i + 4 <= e; i += 4) {
        a0 += h[(size_t)i * HC + c];
        a1 += h[(size_t)(i + 1) * HC + c];
        a2 += h[(size_t)(i + 2) * HC + c];
        a3 += h[(size_t)(i + 3) * HC + c];
    }
    for (; i < e; ++i) a0 += h[(size_t)i * HC + c];
    float acc = (a0 + a1) + (a2 + a3);
    out[g * HC + c] = acc / fmaxf((float)(e - s), 1.f);
}

// ---------------------------------------------------------------------------
extern "C" void kernel_launch(void* const* d_in, const int* in_sizes, int n_in,
                              void* d_out, int out_size, void* d_ws, size_t ws_size,
                              hipStream_t stream) {
    const float* x     = (const float*)d_in[0];
    const float* ea    = (const float*)d_in[1];
    const int*   ei    = (const int*)d_in[2];
    const int*   batch = (const int*)d_in[3];
    const float* Wq1 = (const float*)d_in[4];
    const float* Wk1 = (const float*)d_in[5];
    const float* Wv1 = (const float*)d_in[6];
    const float* We1 = (const float*)d_in[7];
    const float* Ws1 = (const float*)d_in[8];
    const float* Wq2 = (const float*)d_in[9];
    const float* Wk2 = (const float*)d_in[10];
    const float* Wv2 = (const float*)d_in[11];
    const float* We2 = (const float*)d_in[12];
    const float* Ws2 = (const float*)d_in[13];
    const float* bq1 = (const float*)d_in[14];
    const float* bk1 = (const float*)d_in[15];
    const float* bv1 = (const float*)d_in[16];
    const float* be1 = (const float*)d_in[17];
    const float* bs1 = (const float*)d_in[18];
    const float* bq2 = (const float*)d_in[19];
    const float* bk2 = (const float*)d_in[20];
    const float* bv2 = (const float*)d_in[21];
    const float* be2 = (const float*)d_in[22];
    const float* bs2 = (const float*)d_in[23];
    float* out = (float*)d_out;

    char* ws = (char*)d_ws;
    size_t off = 0;
    auto alloc = [&](size_t bytes) -> void* {
        void* p = ws + off;
        off += (bytes + 255) & ~(size_t)255;
        return p;
    };
    int*    cnt    = (int*)alloc((size_t)N_NODES * 4);
    BEntry* bucket = (BEntry*)alloc((size_t)N_NODES * BUCKET_CAP * sizeof(BEntry));
    float*  q      = (float*)alloc((size_t)N_NODES * HC * 4);
    float*  kv     = (float*)alloc((size_t)N_NODES * 128 * 4);
    float*  h1     = (float*)alloc((size_t)N_NODES * HC * 4);
    float*  h2     = (float*)alloc((size_t)N_NODES * HC * 4);
    ushort* wf1_hi = (ushort*)alloc((size_t)4 * 1024 * 8 * 2);
    ushort* wf1_lo = (ushort*)alloc((size_t)4 * 1024 * 8 * 2);
    ushort* wf2_hi = (ushort*)alloc((size_t)4 * 512 * 8 * 2);
    ushort* wf2_lo = (ushort*)alloc((size_t)4 * 512 * 8 * 2);

    hipMemsetAsync(cnt, 0, (size_t)N_NODES * 4, stream);
    build_buckets<<<N_EDGES / 256, 256, 0, stream>>>(ei, ea, cnt, bucket);
    pack_weights<<<24, 256, 0, stream>>>(Wq1, Wk1, Wv1, Ws1, Wq2, Wk2, Wv2, Ws2,
                                         wf1_hi, wf1_lo, wf2_hi, wf2_lo);

    // ---- layer 1 ----
    node_gemm_mfma<IN_CH><<<N_NODES / 128, 256, 0, stream>>>(
        x, wf1_hi, wf1_lo, bq1, bk1, bv1, bs1, q, kv, h1);
    aggregate<1><<<N_NODES / 4, 256, 0, stream>>>(
        q, kv, We1, be1, cnt, bucket, h1);

    // ---- layer 2 ----
    node_gemm_mfma<HC><<<N_NODES / 128, 256, 0, stream>>>(
        h1, wf2_hi, wf2_lo, bq2, bk2, bv2, bs2, q, kv, h2);
    aggregate<0><<<N_NODES / 4, 256, 0, stream>>>(
        q, kv, We2, be2, cnt, bucket, h2);

    // ---- mean pool ----
    pool_graph<<<N_GRAPHS / 4, 256, 0, stream>>>(h2, batch, out);
}